// Round 16
// baseline (231.074 us; speedup 1.0000x reference)
//
#include <hip/hip_runtime.h>

// ---------------------------------------------------------------------------
// minerva_35124242547419 — R23: corrected fused double-buffer (R18 redux with
// all three diagnosed failure causes fixed):
//  (a) Vs swizzled (src chunk ^= row&3, involution on read) — R18's linear
//      Vs was the 8-way-conflict source;
//  (b) 2D wave split (wy over e, wx over q) — af reads stay 8/iter/wave
//      (R18's q-only split doubled them);
//  (c) DMA(t+1) issued at iter TOP into the free buffer -> full-iter cover
//      before its end-of-iter drain (R16 gave it only ~250cyc).
// e-tile 32, 32 iters, LDS 46KB (Ks[2]32K + Vs[2]4K + Us[128][40] 10K),
// lb(256,2) (no spill possible). 2 barriers/iter.
// proj (frag-major W3) / prep / finalize byte-identical to R22 (225.8us).
// Falsifiers (pre-committed): WRITE_SIZE>12MB or fused>=53us -> revert R22.
// I/O contract (R4-R6): f32 inputs resolved BY SIZE, f32 output.
// ---------------------------------------------------------------------------

typedef __bf16 bf16x8 __attribute__((ext_vector_type(8)));
typedef __bf16 bf16x4 __attribute__((ext_vector_type(4)));
typedef float  f32x4  __attribute__((ext_vector_type(4)));

__device__ __forceinline__ f32x4 f4zero() { f32x4 z = {0.f, 0.f, 0.f, 0.f}; return z; }

__device__ __forceinline__ f32x4 mfma16(bf16x8 a, bf16x8 b, f32x4 c) {
  return __builtin_amdgcn_mfma_f32_16x16x32_bf16(a, b, c, 0, 0, 0);
}

// 8 consecutive f32 -> bf16x8
__device__ __forceinline__ bf16x8 load8f(const float* p) {
  f32x4 a = *(const f32x4*)p;
  f32x4 b = *(const f32x4*)(p + 4);
  bf16x8 r;
  r[0] = (__bf16)a[0]; r[1] = (__bf16)a[1]; r[2] = (__bf16)a[2]; r[3] = (__bf16)a[3];
  r[4] = (__bf16)b[0]; r[5] = (__bf16)b[1]; r[6] = (__bf16)b[2]; r[7] = (__bf16)b[3];
  return r;
}

__device__ __forceinline__ bf16x8 cvt2(f32x4 a, f32x4 b) {
  bf16x8 r;
  r[0] = (__bf16)a[0]; r[1] = (__bf16)a[1]; r[2] = (__bf16)a[2]; r[3] = (__bf16)a[3];
  r[4] = (__bf16)b[0]; r[5] = (__bf16)b[1]; r[6] = (__bf16)b[2]; r[7] = (__bf16)b[3];
  return r;
}

// async 16B global -> LDS (wave-uniform base + lane*16 dest; per-lane gsrc)
__device__ __forceinline__ void async16(const void* g, void* l) {
  __builtin_amdgcn_global_load_lds(
      (const __attribute__((address_space(1))) unsigned int*)g,
      (__attribute__((address_space(3))) unsigned int*)l, 16, 0, 0);
}

// raw barrier helpers
__device__ __forceinline__ void bar_lgkm() {
  asm volatile("s_waitcnt lgkmcnt(0)" ::: "memory");
  __builtin_amdgcn_s_barrier();
}
__device__ __forceinline__ void bar_all() {
  asm volatile("s_waitcnt vmcnt(0) lgkmcnt(0)" ::: "memory");
  __builtin_amdgcn_s_barrier();
}

__global__ void fill_sentinel(float* __restrict__ out, int n) {
  for (int i = blockIdx.x * 256 + threadIdx.x; i < n; i += gridDim.x * 256) out[i] = -1.0f;
}

// ---------------------------------------------------------------------------
// prep: (a) build_vt, (b) W f32 -> fragment-major packed bf16 W3, (c) zero.
// W3 layout: frag_id = c16*32 + k32; within a frag 64 lanes x 16B (1KB):
// lane l (quad=l>>4, l15=l&15) holds W[c16*16+l15][k32*32+quad*8 .. +8].
// ---------------------------------------------------------------------------
__global__ void prep(const float* __restrict__ exc, __bf16* __restrict__ vT,
                     const float* __restrict__ W, __bf16* __restrict__ W3,
                     float* __restrict__ zp, int zn) {
  const int b = blockIdx.x, tid = threadIdx.x;
  if (b < 64) {
    int e = b * 256 + tid;
    float m[28];
    float s = 0.f;
#pragma unroll
    for (int j = 0; j < 28; j++) {
      m[j] = exc[(size_t)e * 28 + j];
      s += fabsf(m[j]);
    }
    float inv = 1.0f / fmaxf(s, 1e-12f);
#pragma unroll
    for (int j = 0; j < 28; j++) vT[(size_t)j * 16384 + e] = (__bf16)(m[j] * inv);
#pragma unroll
    for (int j = 28; j < 32; j++) vT[(size_t)j * 16384 + e] = (__bf16)0.0f;
  } else if (b < 192) {
    int i = (b - 64) * 256 + tid;  // chunk id = frag*64 + lane
    int frag = i >> 6, lane = i & 63;
    int c16 = frag >> 5, k32 = frag & 31;
    int quad = lane >> 4, l15 = lane & 15;
    *(bf16x8*)(W3 + (size_t)i * 8) =
        load8f(W + (size_t)(c16 * 16 + l15) * 1024 + k32 * 32 + quad * 8);
  } else {
    for (int i = (b - 192) * 256 + tid; i < zn; i += (gridDim.x - 192) * 256) zp[i] = 0.f;
  }
}

// ---------------------------------------------------------------------------
// P = l2norm_rows(X @ W^T). R16 geometry: 32 rows x 256 cols, BK=64,
// 4 waves side-by-side in N; B-frags from packed W3 (one coalesced 1KB
// stream access per frag). Xs [2][32][72] dbuf, 1 lgkm-barrier/iter.
// LDS 9.5 KB -> 3 blk/CU; grid 640 (0..511 ex_feat, 512..639 features).
// ---------------------------------------------------------------------------
__global__ __launch_bounds__(256, 3)
void proj_l2norm(const float* __restrict__ Xa, const float* __restrict__ Xb,
                 const __bf16* __restrict__ W3,
                 __bf16* __restrict__ Pa, __bf16* __restrict__ Pb) {
  __shared__ __align__(16) __bf16 Xs[2][32 * 72];  // 9.2 KB
  __shared__ float nrmW[4 * 32];
  __shared__ float invn[32];

  const int tid = threadIdx.x;
  const int w = tid >> 6, lane = tid & 63;
  const int quad = lane >> 4, l15 = lane & 15;
  const int xrow = tid >> 3, xc8 = tid & 7;

  const float* X;
  __bf16* P;
  int row0;
  if (blockIdx.x < 512) { X = Xa; P = Pa; row0 = blockIdx.x * 32; }
  else                  { X = Xb; P = Pb; row0 = (blockIdx.x - 512) * 32; }

  const float* xsrc = X + (size_t)(row0 + xrow) * 1024 + xc8 * 8;
  const __bf16* wpk = W3 + (size_t)(w * 4) * 32 * 512 + (size_t)lane * 8;

  f32x4 acc[2][4];
#pragma unroll
  for (int i = 0; i < 2; i++)
#pragma unroll
    for (int j = 0; j < 4; j++) acc[i][j] = f4zero();

  *(bf16x8*)(&Xs[0][xrow * 72 + xc8 * 8]) = load8f(xsrc);
  bar_lgkm();

  int cur = 0;
  for (int kb = 0; kb < 16; kb++) {
    const int nxt = cur ^ 1;

    bf16x8 wF[8];
#pragma unroll
    for (int f = 0; f < 8; f++) {
      const int ksub = f >> 2, nb = f & 3;
      wF[f] = *(const bf16x8*)(wpk + ((size_t)nb * 32 + kb * 2 + ksub) * 512);
    }

    f32x4 xa, xb;
    if (kb < 15) {
      const float* xp = xsrc + (kb + 1) * 64;
      xa = *(const f32x4*)xp;
      xb = *(const f32x4*)(xp + 4);
    }

#pragma unroll
    for (int ksub = 0; ksub < 2; ksub++) {
      bf16x8 af[2];
#pragma unroll
      for (int mb = 0; mb < 2; mb++)
        af[mb] = *(bf16x8*)(&Xs[cur][(mb * 16 + l15) * 72 + ksub * 32 + quad * 8]);
#pragma unroll
      for (int mb = 0; mb < 2; mb++)
#pragma unroll
        for (int nb = 0; nb < 4; nb++)
          acc[mb][nb] = mfma16(af[mb], wF[ksub * 4 + nb], acc[mb][nb]);
    }

    if (kb < 15) {
      *(bf16x8*)(&Xs[nxt][xrow * 72 + xc8 * 8]) = cvt2(xa, xb);
    }
    bar_lgkm();
    cur = nxt;
  }

  float part[2][4];
#pragma unroll
  for (int mb = 0; mb < 2; mb++)
#pragma unroll
    for (int r = 0; r < 4; r++) {
      float s = 0.f;
#pragma unroll
      for (int nb = 0; nb < 4; nb++) { float v = acc[mb][nb][r]; s += v * v; }
      part[mb][r] = s;
    }
#pragma unroll
  for (int m = 1; m < 16; m <<= 1)
#pragma unroll
    for (int mb = 0; mb < 2; mb++)
#pragma unroll
      for (int r = 0; r < 4; r++) part[mb][r] += __shfl_xor(part[mb][r], m, 64);

  if (l15 == 0) {
#pragma unroll
    for (int mb = 0; mb < 2; mb++)
#pragma unroll
      for (int r = 0; r < 4; r++)
        nrmW[w * 32 + mb * 16 + quad * 4 + r] = part[mb][r];
  }
  __syncthreads();
  if (tid < 32) {
    float s = nrmW[tid] + nrmW[32 + tid] + nrmW[64 + tid] + nrmW[96 + tid];
    invn[tid] = 1.0f / fmaxf(sqrtf(s), 1e-12f);
  }
  __syncthreads();
#pragma unroll
  for (int mb = 0; mb < 2; mb++)
#pragma unroll
    for (int nb = 0; nb < 4; nb++)
#pragma unroll
      for (int r = 0; r < 4; r++) {
        int row = mb * 16 + quad * 4 + r;
        int col = w * 64 + nb * 16 + l15;
        P[(size_t)(row0 + row) * 256 + col] = (__bf16)(acc[mb][nb][r] * invn[row]);
      }
}

// ---------------------------------------------------------------------------
// Fused flash-style pass — R23 corrected double-buffer.
// e-tile 32, 32 iters. Per iter:
//   [issue DMA Ks[nxt],Vs[nxt] <- tile t+1]   (full-iter cover)
//   QK(Ks[cur]) -> accs[4]   (wave = wy e-half x wx q-half; af 8 reads)
//   Us write (power-sign, rows [128 q][40])
//   bar_lgkm   (Ks[cur] reads retired; Us visible; DMA stays in flight)
//   PV(Vs[cur], Us)   (wave w owns 32 q)
//   bar_all    (DMA issued a full iter ago drains ~free; reads retired)
// LDS: Ks[2][32][256] 32K + Vs[2][32][32] 4K (swizzled) + Us 10K = 46 KB.
// ---------------------------------------------------------------------------
__global__ __launch_bounds__(256, 2)
void fused_sim(const __bf16* __restrict__ fn, const __bf16* __restrict__ efn,
               const __bf16* __restrict__ vTg,
               float* __restrict__ tT, float* __restrict__ r_acc) {
  __shared__ __align__(16) __bf16 Ks[2][32 * 256];  // 32 KB, swizzled dbuf
  __shared__ __align__(16) __bf16 Vs[2][32 * 32];   // 4 KB, swizzled dbuf
  __shared__ __align__(16) __bf16 Us[128 * 40];     // 10 KB, pad 40

  const int tid = threadIdx.x, w = tid >> 6, lane = tid & 63;
  const int quad = lane >> 4, l15 = lane & 15;
  const int wy = w >> 1, wx = w & 1;
  const int swk = l15 & 7;
  const int chunk = blockIdx.x & 15, mtile = blockIdx.x >> 4;
  const int q0 = mtile * 128;
  const int e_base = chunk * 1024;

  // Ks staging: 1024 chunks (32 rows x 32), 4/thread, swizzled source
  int koff[4];
#pragma unroll
  for (int rep = 0; rep < 4; rep++) {
    int idx = rep * 256 + tid;       // row = idx>>5 (0..31), chunk c5' = idx&31
    int row = idx >> 5;
    int c5  = (idx & 31) ^ (row & 7);
    koff[rep] = row * 256 + c5 * 8;
  }
  // Vs staging: 128 chunks (32 classes x 4), threads 0..127, swizzled source
  const int vrow = tid >> 2;
  const int vcs  = (tid & 3) ^ (vrow & 3);
  const bool vstage = (tid < 128);

  // prologue: DMA tile 0
  {
    const __bf16* src = efn + (size_t)e_base * 256;
#pragma unroll
    for (int rep = 0; rep < 4; rep++)
      async16(src + koff[rep], &Ks[0][(rep * 256 + tid) * 8]);
    if (vstage)
      async16(vTg + (size_t)vrow * 16384 + e_base + vcs * 8, &Vs[0][tid * 8]);
  }

  // Q fragments: wave's q-half (wx), 64 q x 256 K
  bf16x8 qf[8][4];
#pragma unroll
  for (int ks = 0; ks < 8; ks++)
#pragma unroll
    for (int nb = 0; nb < 4; nb++)
      qf[ks][nb] = *(const bf16x8*)(fn + (size_t)(q0 + wx * 64 + nb * 16 + l15) * 256 +
                                    ks * 32 + quad * 8);

  float r_part[4] = {0.f, 0.f, 0.f, 0.f};
  f32x4 accp[2][2];
#pragma unroll
  for (int a = 0; a < 2; a++)
#pragma unroll
    for (int b = 0; b < 2; b++) accp[a][b] = f4zero();

  bar_all();  // tile 0 + qf ready

  int cur = 0;
  for (int t = 0; t < 32; t++) {
    const int nxt = cur ^ 1;

    // issue DMA for tile t+1 into the FREE buffer. Ks[nxt] was last read at
    // QK(t-1) (drained at t-1's bar_lgkm, all waves past t-1's bar_all);
    // Vs[nxt] last read at PV(t-1) (drained at t-1's bar_all).
    if (t < 31) {
      const __bf16* src = efn + (size_t)(e_base + (t + 1) * 32) * 256;
#pragma unroll
      for (int rep = 0; rep < 4; rep++)
        async16(src + koff[rep], &Ks[nxt][(rep * 256 + tid) * 8]);
      if (vstage)
        async16(vTg + (size_t)vrow * 16384 + e_base + (t + 1) * 32 + vcs * 8,
                &Vs[nxt][tid * 8]);
    }

    // ---- QK: wave computes its (wy e-half) x (wx q-half) ----
    f32x4 accs[4];
#pragma unroll
    for (int b = 0; b < 4; b++) accs[b] = f4zero();
#pragma unroll
    for (int ks = 0; ks < 8; ks++) {
      bf16x8 af = *(bf16x8*)(&Ks[cur][(wy * 16 + l15) * 256 +
                                      ((ks * 4 + quad) ^ swk) * 8]);
#pragma unroll
      for (int nb = 0; nb < 4; nb++)
        accs[nb] = mfma16(af, qf[ks][nb], accs[nb]);
    }

    // ---- Us write: power-sign + |.| partial ----
    const int eo = wy * 16 + quad * 4;
#pragma unroll
    for (int nb = 0; nb < 4; nb++) {
      bf16x4 pk;
#pragma unroll
      for (int r = 0; r < 4; r++) {
        float s = accs[nb][r];
        __bf16 ub = (__bf16)(s * s * s);
        pk[r] = ub;
        r_part[nb] += fabsf((float)ub);
      }
      *(bf16x4*)(&Us[(wx * 64 + nb * 16 + l15) * 40 + eo]) = pk;
    }

    bar_lgkm();  // Ks[cur] reads retired + Us visible; DMA stays in flight

    // ---- PV: wave w owns q rows [w*32,+32); k = 32 e (1 MFMA-K step) ----
    {
      bf16x8 vf[2], uf[2];
#pragma unroll
      for (int cb = 0; cb < 2; cb++) {
        const int vr = cb * 16 + l15;
        vf[cb] = *(bf16x8*)(&Vs[cur][vr * 32 + (quad ^ (vr & 3)) * 8]);
      }
#pragma unroll
      for (int qb = 0; qb < 2; qb++)
        uf[qb] = *(bf16x8*)(&Us[(w * 32 + qb * 16 + l15) * 40 + quad * 8]);
#pragma unroll
      for (int cb = 0; cb < 2; cb++)
#pragma unroll
        for (int qb = 0; qb < 2; qb++)
          accp[cb][qb] = mfma16(vf[cb], uf[qb], accp[cb][qb]);
    }

    bar_all();  // DMA(t+1) landed (full-iter cover); PV reads retired
    cur = nxt;
  }

  // ---- epilogue ----
#pragma unroll
  for (int nb = 0; nb < 4; nb++) {
    float v = r_part[nb];
    v += __shfl_xor(v, 16, 64);
    v += __shfl_xor(v, 32, 64);
    if (quad == 0) atomicAdd(&r_acc[q0 + wx * 64 + nb * 16 + l15], v);
  }
#pragma unroll
  for (int cb = 0; cb < 2; cb++)
#pragma unroll
    for (int qb = 0; qb < 2; qb++)
#pragma unroll
      for (int r = 0; r < 4; r++)
        atomicAdd(&tT[(size_t)(cb * 16 + quad * 4 + r) * 4096 + q0 + w * 32 + qb * 16 + l15],
                  accp[cb][qb][r]);
}

// ---------------------------------------------------------------------------
// finalize: WAVE-PER-QUERY + fused loss write (last-block pattern).
// ---------------------------------------------------------------------------
__global__ __launch_bounds__(256, 4)
void finalize(const float* __restrict__ tT, const float* __restrict__ r_acc,
              const float* __restrict__ creps, const float* __restrict__ labels,
              float* __restrict__ loss_acc, float* __restrict__ out) {
  __shared__ __align__(16) float cr[28 * 64];
  __shared__ float wsum[4];
  const int tid = threadIdx.x, w = tid >> 6, lane = tid & 63;
  for (int i = tid; i < 28 * 64; i += 256) cr[i] = creps[i];
  __syncthreads();

  const int q = blockIdx.x * 4 + w;
  float tval = 0.f;
  if (lane < 28) tval = tT[(size_t)lane * 4096 + q];
  tval *= 1.0f / fmaxf(r_acc[q], 1e-12f);

  float echo = 0.f;
#pragma unroll
  for (int j = 0; j < 28; j++)
    echo = fmaf(__shfl(tval, j, 64), cr[j * 64 + lane], echo);

  float dj = 0.f;
#pragma unroll
  for (int j = 0; j < 28; j++) {
    float df = echo - cr[j * 64 + lane];
    float d2 = df * df;
#pragma unroll
    for (int m = 1; m < 64; m <<= 1) d2 += __shfl_xor(d2, m, 64);
    if (lane == j) dj = sqrtf(d2);
  }

  float lsum = 0.f;
  if (lane < 28) {
    out[1 + (size_t)q * 28 + lane] = -dj;
    float y = labels[(size_t)q * 28 + lane];
    lsum = fmaf(y, dj, log1pf(expf(-dj)));  // BCEWithLogits(-d, y), d >= 0
  }
#pragma unroll
  for (int m = 1; m < 64; m <<= 1) lsum += __shfl_xor(lsum, m, 64);
  if (lane == 0) wsum[w] = lsum;
  __syncthreads();
  if (tid == 0) {
    atomicAdd(loss_acc, wsum[0] + wsum[1] + wsum[2] + wsum[3]);
    __threadfence();
    unsigned* cnt = (unsigned*)(loss_acc + 1);
    unsigned old = atomicAdd(cnt, 1u);
    if (old == gridDim.x - 1) {
      float total = atomicAdd(loss_acc, 0.0f);
      out[0] = total * (1.0f / 114688.0f);
    }
  }
}

// ---------------------------------------------------------------------------
extern "C" void kernel_launch(void* const* d_in, const int* in_sizes, int n_in,
                              void* d_out, int out_size, void* d_ws, size_t ws_size,
                              hipStream_t stream) {
  // Resolve inputs BY ELEMENT COUNT (unique per input; permutation-proof).
  const float* features = nullptr;  // 4096*1024   = 4194304
  const float* labels   = nullptr;  // 4096*28     = 114688
  const float* ex_feat  = nullptr;  // 16384*1024  = 16777216
  const float* ex_cls   = nullptr;  // 16384*28    = 458752
  const float* g_w      = nullptr;  // 256*1024    = 262144
  const float* creps    = nullptr;  // 28*64       = 1792
  for (int i = 0; i < n_in; i++) {
    switch (in_sizes[i]) {
      case 4194304:  features = (const float*)d_in[i]; break;
      case 114688:   labels   = (const float*)d_in[i]; break;
      case 16777216: ex_feat  = (const float*)d_in[i]; break;
      case 458752:   ex_cls   = (const float*)d_in[i]; break;
      case 262144:   g_w      = (const float*)d_in[i]; break;
      case 1792:     creps    = (const float*)d_in[i]; break;
      default: break;
    }
  }
  float* out = (float*)d_out;  // f32: [loss(1)] ++ [neg_dists 4096*28]

  if (!features || !labels || !ex_feat || !ex_cls || !g_w || !creps ||
      ws_size < (16ull << 20)) {
    fill_sentinel<<<256, 256, 0, stream>>>(out, out_size);  // diagnostic
    return;
  }

  char* ws = (char*)d_ws;
  __bf16* f_n   = (__bf16*)(ws);                    // 2 MB   [4096][256]
  __bf16* ef_n  = (__bf16*)(ws + (2ull << 20));     // 8 MB   [16384][256]
  __bf16* vT    = (__bf16*)(ws + (10ull << 20));    // 1 MB   [32][16384]
  float*  tT    = (float*) (ws + (11ull << 20));    // 512 KB [32][4096]
  float*  r_acc = tT + 32 * 4096;                   // 16 KB
  float*  lossp = r_acc + 4096;                     // 8 B (loss + done-counter)
  __bf16* W3    = (__bf16*)(ws + (12ull << 20));    // 512 KB fragment-major W

  prep<<<720, 256, 0, stream>>>(ex_cls, vT, g_w, W3, tT, 32 * 4096 + 4096 + 2);

  proj_l2norm<<<640, 256, 0, stream>>>(ex_feat, features, W3, ef_n, f_n);
  fused_sim<<<512, 256, 0, stream>>>(f_n, ef_n, vT, tT, r_acc);
  finalize<<<1024, 256, 0, stream>>>(tT, r_acc, creps, labels, lossp, out);
}

// Round 17
// 222.264 us; speedup vs baseline: 1.0396x; 1.0396x over previous
//
#include <hip/hip_runtime.h>

// ---------------------------------------------------------------------------
// minerva_35124242547419 — R24: byte-exact revert to R22 (session best,
// 225.8us measured, fused 53.2-53.7 reproduced twice).
// Final fused verdict (R18 + R23, both refcheck-clean): e-tile-32 double
// buffering costs more in barriers (64 vs 48) + halved MFMA-per-interval
// than the full-iter DMA cover recovers. The R16/R11 single-Ks deferred-
// drain @ e-tile 64 is the optimum of the barrier-loop family here.
// Config: proj = frag-major W3 stream; fused = R11 deferred-drain pipeline
// (Ks swizzled + Vs swizzled dbuf + Us pad72, lb(256,2)); prep = vT+W3+zero;
// finalize = wave-per-query + last-block loss.
// I/O contract (R4-R6): f32 inputs resolved BY SIZE, f32 output.
// ---------------------------------------------------------------------------

typedef __bf16 bf16x8 __attribute__((ext_vector_type(8)));
typedef __bf16 bf16x4 __attribute__((ext_vector_type(4)));
typedef float  f32x4  __attribute__((ext_vector_type(4)));

__device__ __forceinline__ f32x4 f4zero() { f32x4 z = {0.f, 0.f, 0.f, 0.f}; return z; }

__device__ __forceinline__ f32x4 mfma16(bf16x8 a, bf16x8 b, f32x4 c) {
  return __builtin_amdgcn_mfma_f32_16x16x32_bf16(a, b, c, 0, 0, 0);
}

// 8 consecutive f32 -> bf16x8
__device__ __forceinline__ bf16x8 load8f(const float* p) {
  f32x4 a = *(const f32x4*)p;
  f32x4 b = *(const f32x4*)(p + 4);
  bf16x8 r;
  r[0] = (__bf16)a[0]; r[1] = (__bf16)a[1]; r[2] = (__bf16)a[2]; r[3] = (__bf16)a[3];
  r[4] = (__bf16)b[0]; r[5] = (__bf16)b[1]; r[6] = (__bf16)b[2]; r[7] = (__bf16)b[3];
  return r;
}

__device__ __forceinline__ bf16x8 cvt2(f32x4 a, f32x4 b) {
  bf16x8 r;
  r[0] = (__bf16)a[0]; r[1] = (__bf16)a[1]; r[2] = (__bf16)a[2]; r[3] = (__bf16)a[3];
  r[4] = (__bf16)b[0]; r[5] = (__bf16)b[1]; r[6] = (__bf16)b[2]; r[7] = (__bf16)b[3];
  return r;
}

// async 16B global -> LDS (wave-uniform base + lane*16 dest; per-lane gsrc)
__device__ __forceinline__ void async16(const void* g, void* l) {
  __builtin_amdgcn_global_load_lds(
      (const __attribute__((address_space(1))) unsigned int*)g,
      (__attribute__((address_space(3))) unsigned int*)l, 16, 0, 0);
}

// raw barrier helpers
__device__ __forceinline__ void bar_lgkm() {
  asm volatile("s_waitcnt lgkmcnt(0)" ::: "memory");
  __builtin_amdgcn_s_barrier();
}
__device__ __forceinline__ void bar_all() {
  asm volatile("s_waitcnt vmcnt(0) lgkmcnt(0)" ::: "memory");
  __builtin_amdgcn_s_barrier();
}

__global__ void fill_sentinel(float* __restrict__ out, int n) {
  for (int i = blockIdx.x * 256 + threadIdx.x; i < n; i += gridDim.x * 256) out[i] = -1.0f;
}

// ---------------------------------------------------------------------------
// prep: (a) build_vt, (b) W f32 -> fragment-major packed bf16 W3, (c) zero.
// W3 layout: frag_id = c16*32 + k32; within a frag 64 lanes x 16B (1KB):
// lane l (quad=l>>4, l15=l&15) holds W[c16*16+l15][k32*32+quad*8 .. +8].
// ---------------------------------------------------------------------------
__global__ void prep(const float* __restrict__ exc, __bf16* __restrict__ vT,
                     const float* __restrict__ W, __bf16* __restrict__ W3,
                     float* __restrict__ zp, int zn) {
  const int b = blockIdx.x, tid = threadIdx.x;
  if (b < 64) {
    int e = b * 256 + tid;
    float m[28];
    float s = 0.f;
#pragma unroll
    for (int j = 0; j < 28; j++) {
      m[j] = exc[(size_t)e * 28 + j];
      s += fabsf(m[j]);
    }
    float inv = 1.0f / fmaxf(s, 1e-12f);
#pragma unroll
    for (int j = 0; j < 28; j++) vT[(size_t)j * 16384 + e] = (__bf16)(m[j] * inv);
#pragma unroll
    for (int j = 28; j < 32; j++) vT[(size_t)j * 16384 + e] = (__bf16)0.0f;
  } else if (b < 192) {
    int i = (b - 64) * 256 + tid;  // chunk id = frag*64 + lane
    int frag = i >> 6, lane = i & 63;
    int c16 = frag >> 5, k32 = frag & 31;
    int quad = lane >> 4, l15 = lane & 15;
    *(bf16x8*)(W3 + (size_t)i * 8) =
        load8f(W + (size_t)(c16 * 16 + l15) * 1024 + k32 * 32 + quad * 8);
  } else {
    for (int i = (b - 192) * 256 + tid; i < zn; i += (gridDim.x - 192) * 256) zp[i] = 0.f;
  }
}

// ---------------------------------------------------------------------------
// P = l2norm_rows(X @ W^T). Block: 32 rows x 256 cols, BK=64, 16 k-iters,
// 4 waves side-by-side in N (wave w: cols w*64..+63). B-frags from packed
// W3: one coalesced 1KB stream access per frag (frag_id = (w*4+nb)*32 +
// kb*2 + ksub; addr = frag_id*512 + lane*8). Xs: [2][32][72] bf16 dbuf,
// 1 chunk/thread, 1 lgkm-barrier/iter. LDS 9.5 KB -> 3 blk/CU; grid 640
// (0..511 ex_feat, 512..639 features).
// ---------------------------------------------------------------------------
__global__ __launch_bounds__(256, 3)
void proj_l2norm(const float* __restrict__ Xa, const float* __restrict__ Xb,
                 const __bf16* __restrict__ W3,
                 __bf16* __restrict__ Pa, __bf16* __restrict__ Pb) {
  __shared__ __align__(16) __bf16 Xs[2][32 * 72];  // 9.2 KB
  __shared__ float nrmW[4 * 32];
  __shared__ float invn[32];

  const int tid = threadIdx.x;
  const int w = tid >> 6, lane = tid & 63;
  const int quad = lane >> 4, l15 = lane & 15;
  const int xrow = tid >> 3, xc8 = tid & 7;  // Xs staging coords

  const float* X;
  __bf16* P;
  int row0;
  if (blockIdx.x < 512) { X = Xa; P = Pa; row0 = blockIdx.x * 32; }
  else                  { X = Xb; P = Pb; row0 = (blockIdx.x - 512) * 32; }

  const float* xsrc = X + (size_t)(row0 + xrow) * 1024 + xc8 * 8;
  // wave-private packed-W base: frags (w*4+nb)*32 + (kb*2+ksub), lane-major
  const __bf16* wpk = W3 + (size_t)(w * 4) * 32 * 512 + (size_t)lane * 8;

  f32x4 acc[2][4];
#pragma unroll
  for (int i = 0; i < 2; i++)
#pragma unroll
    for (int j = 0; j < 4; j++) acc[i][j] = f4zero();

  // prologue: stage Xs[0](kb=0)
  *(bf16x8*)(&Xs[0][xrow * 72 + xc8 * 8]) = load8f(xsrc);
  bar_lgkm();

  int cur = 0;
  for (int kb = 0; kb < 16; kb++) {
    const int nxt = cur ^ 1;

    // W frags for this kb: 8 coalesced 1KB stream loads (per wave)
    bf16x8 wF[8];
#pragma unroll
    for (int f = 0; f < 8; f++) {
      const int ksub = f >> 2, nb = f & 3;
      wF[f] = *(const bf16x8*)(wpk + ((size_t)nb * 32 + kb * 2 + ksub) * 512);
    }

    // prefetch next X slab to regs (flies across compute)
    f32x4 xa, xb;
    if (kb < 15) {
      const float* xp = xsrc + (kb + 1) * 64;
      xa = *(const f32x4*)xp;
      xb = *(const f32x4*)(xp + 4);
    }

    // compute: 2 ksub x (2 af ds_read + 4 MFMA)
#pragma unroll
    for (int ksub = 0; ksub < 2; ksub++) {
      bf16x8 af[2];
#pragma unroll
      for (int mb = 0; mb < 2; mb++)
        af[mb] = *(bf16x8*)(&Xs[cur][(mb * 16 + l15) * 72 + ksub * 32 + quad * 8]);
#pragma unroll
      for (int mb = 0; mb < 2; mb++)
#pragma unroll
        for (int nb = 0; nb < 4; nb++)
          acc[mb][nb] = mfma16(af[mb], wF[ksub * 4 + nb], acc[mb][nb]);
    }

    if (kb < 15) {
      *(bf16x8*)(&Xs[nxt][xrow * 72 + xc8 * 8]) = cvt2(xa, xb);
    }
    bar_lgkm();
    cur = nxt;
  }

  // row sum-of-squares: in-lane over nb, shfl over l15, cross-wave via LDS
  float part[2][4];
#pragma unroll
  for (int mb = 0; mb < 2; mb++)
#pragma unroll
    for (int r = 0; r < 4; r++) {
      float s = 0.f;
#pragma unroll
      for (int nb = 0; nb < 4; nb++) { float v = acc[mb][nb][r]; s += v * v; }
      part[mb][r] = s;
    }
#pragma unroll
  for (int m = 1; m < 16; m <<= 1)
#pragma unroll
    for (int mb = 0; mb < 2; mb++)
#pragma unroll
      for (int r = 0; r < 4; r++) part[mb][r] += __shfl_xor(part[mb][r], m, 64);

  if (l15 == 0) {
#pragma unroll
    for (int mb = 0; mb < 2; mb++)
#pragma unroll
      for (int r = 0; r < 4; r++)
        nrmW[w * 32 + mb * 16 + quad * 4 + r] = part[mb][r];
  }
  __syncthreads();
  if (tid < 32) {
    float s = nrmW[tid] + nrmW[32 + tid] + nrmW[64 + tid] + nrmW[96 + tid];
    invn[tid] = 1.0f / fmaxf(sqrtf(s), 1e-12f);
  }
  __syncthreads();
#pragma unroll
  for (int mb = 0; mb < 2; mb++)
#pragma unroll
    for (int nb = 0; nb < 4; nb++)
#pragma unroll
      for (int r = 0; r < 4; r++) {
        int row = mb * 16 + quad * 4 + r;
        int col = w * 64 + nb * 16 + l15;
        P[(size_t)(row0 + row) * 256 + col] = (__bf16)(acc[mb][nb][r] * invn[row]);
      }
}

// ---------------------------------------------------------------------------
// Fused flash-style pass — R11/R16 deferred-drain pipeline (known 53-56us).
// Per t-iter: QK(t) | lgkm-bar | issue DMA Ks(t+1),Vs(t+1) | Us write |
// lgkm-bar | PV(t) | vmcnt0-bar.
// LDS: Ks 32K (swizzled) + Vs[2] 8K (swizzled dbuf) + Us 18K (pad 72).
// ---------------------------------------------------------------------------
__global__ __launch_bounds__(256, 2)
void fused_sim(const __bf16* __restrict__ fn, const __bf16* __restrict__ efn,
               const __bf16* __restrict__ vTg,
               float* __restrict__ tT, float* __restrict__ r_acc) {
  __shared__ __align__(16) __bf16 Ks[64 * 256];    // 32 KB, swizzled
  __shared__ __align__(16) __bf16 Vs[2][32 * 64];  // 8 KB, swizzled, dbuf
  __shared__ __align__(16) __bf16 Us[128 * 72];    // 18 KB

  const int tid = threadIdx.x, w = tid >> 6, lane = tid & 63;
  const int quad = lane >> 4, l15 = lane & 15;
  const int wy = w >> 1, wx = w & 1;
  const int swk = l15 & 7;
  const int chunk = blockIdx.x & 15, mtile = blockIdx.x >> 4;
  const int q0 = mtile * 128;
  const int e_base = chunk * 1024;

  int koff[8];
#pragma unroll
  for (int rep = 0; rep < 8; rep++) {
    int idx = rep * 256 + tid;     // row = idx>>5, chunk c5' = idx&31
    int row = idx >> 5;
    int c5  = (idx & 31) ^ (row & 7);
    koff[rep] = row * 256 + c5 * 8;
  }
  const int vrow = tid >> 3;
  const int vcs  = (tid & 7) ^ (vrow & 7);
  const size_t vsrc0 = (size_t)vrow * 16384 + e_base + vcs * 8;

  {
    const __bf16* src = efn + (size_t)e_base * 256;
#pragma unroll
    for (int rep = 0; rep < 8; rep++) async16(src + koff[rep], Ks + (rep * 256 + tid) * 8);
    async16(vTg + vsrc0, &Vs[0][tid * 8]);
  }

  bf16x8 qf[8][4];
#pragma unroll
  for (int ks = 0; ks < 8; ks++)
#pragma unroll
    for (int nb = 0; nb < 4; nb++)
      qf[ks][nb] = *(const bf16x8*)(fn + (size_t)(q0 + wx * 64 + nb * 16 + l15) * 256 +
                                    ks * 32 + quad * 8);

  float r_part[4] = {0.f, 0.f, 0.f, 0.f};
  f32x4 accp[2][2];
#pragma unroll
  for (int a = 0; a < 2; a++)
#pragma unroll
    for (int b = 0; b < 2; b++) accp[a][b] = f4zero();

  bar_all();  // Ks(0), Vs(0), qf ready

  int cur = 0;
  for (int t = 0; t < 16; t++) {
    // ---- QK: reads Ks ----
    f32x4 accs[2][4];
#pragma unroll
    for (int a = 0; a < 2; a++)
#pragma unroll
      for (int b = 0; b < 4; b++) accs[a][b] = f4zero();
#pragma unroll
    for (int ks = 0; ks < 8; ks++) {
      bf16x8 af[2];
#pragma unroll
      for (int mb = 0; mb < 2; mb++)
        af[mb] = *(bf16x8*)(Ks + (wy * 32 + mb * 16 + l15) * 256 +
                            ((ks * 4 + quad) ^ swk) * 8);
#pragma unroll
      for (int mb = 0; mb < 2; mb++)
#pragma unroll
        for (int nb = 0; nb < 4; nb++)
          accs[mb][nb] = mfma16(af[mb], qf[ks][nb], accs[mb][nb]);
    }

    bar_lgkm();  // all waves done reading Ks -> safe to overwrite via DMA

    if (t < 15) {
      const __bf16* src = efn + (size_t)(e_base + (t + 1) * 64) * 256;
#pragma unroll
      for (int rep = 0; rep < 8; rep++)
        async16(src + koff[rep], Ks + (rep * 256 + tid) * 8);
      async16(vTg + vsrc0 + (t + 1) * 64, &Vs[cur ^ 1][tid * 8]);
    }

    // ---- Us write (power-sign + |.| partial) ----
#pragma unroll
    for (int mb = 0; mb < 2; mb++) {
      const int eo = wy * 32 + mb * 16 + quad * 4;
#pragma unroll
      for (int nb = 0; nb < 4; nb++) {
        const int q = wx * 64 + nb * 16 + l15;
        bf16x4 pk;
#pragma unroll
        for (int r = 0; r < 4; r++) {
          float s = accs[mb][nb][r];
          __bf16 ub = (__bf16)(s * s * s);
          pk[r] = ub;
          r_part[nb] += fabsf((float)ub);
        }
        *(bf16x4*)(Us + q * 72 + eo) = pk;
      }
    }

    bar_lgkm();  // Us visible

    // ---- PV: reads Us + Vs[cur] ----
#pragma unroll
    for (int ks = 0; ks < 2; ks++) {
      bf16x8 vf[2], uf[2];
#pragma unroll
      for (int cb = 0; cb < 2; cb++)
        vf[cb] = *(bf16x8*)(&Vs[cur][(cb * 16 + l15) * 64 + ((ks * 4 + quad) ^ swk) * 8]);
#pragma unroll
      for (int qb = 0; qb < 2; qb++)
        uf[qb] = *(bf16x8*)(Us + (w * 32 + qb * 16 + l15) * 72 + ks * 32 + quad * 8);
#pragma unroll
      for (int cb = 0; cb < 2; cb++)
#pragma unroll
        for (int qb = 0; qb < 2; qb++)
          accp[cb][qb] = mfma16(vf[cb], uf[qb], accp[cb][qb]);
    }

    bar_all();  // Ks(t+1)/Vs(t+1) landed, PV reads retired
    cur ^= 1;
  }

#pragma unroll
  for (int nb = 0; nb < 4; nb++) {
    float v = r_part[nb];
    v += __shfl_xor(v, 16, 64);
    v += __shfl_xor(v, 32, 64);
    if (quad == 0) atomicAdd(&r_acc[q0 + wx * 64 + nb * 16 + l15], v);
  }
#pragma unroll
  for (int cb = 0; cb < 2; cb++)
#pragma unroll
    for (int qb = 0; qb < 2; qb++)
#pragma unroll
      for (int r = 0; r < 4; r++)
        atomicAdd(&tT[(size_t)(cb * 16 + quad * 4 + r) * 4096 + q0 + w * 32 + qb * 16 + l15],
                  accp[cb][qb][r]);
}

// ---------------------------------------------------------------------------
// finalize: WAVE-PER-QUERY + fused loss write (last-block pattern).
// ---------------------------------------------------------------------------
__global__ __launch_bounds__(256, 4)
void finalize(const float* __restrict__ tT, const float* __restrict__ r_acc,
              const float* __restrict__ creps, const float* __restrict__ labels,
              float* __restrict__ loss_acc, float* __restrict__ out) {
  __shared__ __align__(16) float cr[28 * 64];
  __shared__ float wsum[4];
  const int tid = threadIdx.x, w = tid >> 6, lane = tid & 63;
  for (int i = tid; i < 28 * 64; i += 256) cr[i] = creps[i];
  __syncthreads();

  const int q = blockIdx.x * 4 + w;
  float tval = 0.f;
  if (lane < 28) tval = tT[(size_t)lane * 4096 + q];
  tval *= 1.0f / fmaxf(r_acc[q], 1e-12f);

  float echo = 0.f;
#pragma unroll
  for (int j = 0; j < 28; j++)
    echo = fmaf(__shfl(tval, j, 64), cr[j * 64 + lane], echo);

  float dj = 0.f;
#pragma unroll
  for (int j = 0; j < 28; j++) {
    float df = echo - cr[j * 64 + lane];
    float d2 = df * df;
#pragma unroll
    for (int m = 1; m < 64; m <<= 1) d2 += __shfl_xor(d2, m, 64);
    if (lane == j) dj = sqrtf(d2);
  }

  float lsum = 0.f;
  if (lane < 28) {
    out[1 + (size_t)q * 28 + lane] = -dj;
    float y = labels[(size_t)q * 28 + lane];
    lsum = fmaf(y, dj, log1pf(expf(-dj)));  // BCEWithLogits(-d, y), d >= 0
  }
#pragma unroll
  for (int m = 1; m < 64; m <<= 1) lsum += __shfl_xor(lsum, m, 64);
  if (lane == 0) wsum[w] = lsum;
  __syncthreads();
  if (tid == 0) {
    atomicAdd(loss_acc, wsum[0] + wsum[1] + wsum[2] + wsum[3]);
    __threadfence();
    unsigned* cnt = (unsigned*)(loss_acc + 1);
    unsigned old = atomicAdd(cnt, 1u);
    if (old == gridDim.x - 1) {
      float total = atomicAdd(loss_acc, 0.0f);
      out[0] = total * (1.0f / 114688.0f);
    }
  }
}

// ---------------------------------------------------------------------------
extern "C" void kernel_launch(void* const* d_in, const int* in_sizes, int n_in,
                              void* d_out, int out_size, void* d_ws, size_t ws_size,
                              hipStream_t stream) {
  // Resolve inputs BY ELEMENT COUNT (unique per input; permutation-proof).
  const float* features = nullptr;  // 4096*1024   = 4194304
  const float* labels   = nullptr;  // 4096*28     = 114688
  const float* ex_feat  = nullptr;  // 16384*1024  = 16777216
  const float* ex_cls   = nullptr;  // 16384*28    = 458752
  const float* g_w      = nullptr;  // 256*1024    = 262144
  const float* creps    = nullptr;  // 28*64       = 1792
  for (int i = 0; i < n_in; i++) {
    switch (in_sizes[i]) {
      case 4194304:  features = (const float*)d_in[i]; break;
      case 114688:   labels   = (const float*)d_in[i]; break;
      case 16777216: ex_feat  = (const float*)d_in[i]; break;
      case 458752:   ex_cls   = (const float*)d_in[i]; break;
      case 262144:   g_w      = (const float*)d_in[i]; break;
      case 1792:     creps    = (const float*)d_in[i]; break;
      default: break;
    }
  }
  float* out = (float*)d_out;  // f32: [loss(1)] ++ [neg_dists 4096*28]

  if (!features || !labels || !ex_feat || !ex_cls || !g_w || !creps ||
      ws_size < (16ull << 20)) {
    fill_sentinel<<<256, 256, 0, stream>>>(out, out_size);  // diagnostic
    return;
  }

  char* ws = (char*)d_ws;
  __bf16* f_n   = (__bf16*)(ws);                    // 2 MB   [4096][256]
  __bf16* ef_n  = (__bf16*)(ws + (2ull << 20));     // 8 MB   [16384][256]
  __bf16* vT    = (__bf16*)(ws + (10ull << 20));    // 1 MB   [32][16384]
  float*  tT    = (float*) (ws + (11ull << 20));    // 512 KB [32][4096]
  float*  r_acc = tT + 32 * 4096;                   // 16 KB
  float*  lossp = r_acc + 4096;                     // 8 B (loss + done-counter)
  __bf16* W3    = (__bf16*)(ws + (12ull << 20));    // 512 KB fragment-major W

  prep<<<720, 256, 0, stream>>>(ex_cls, vT, g_w, W3, tT, 32 * 4096 + 4096 + 2);

  proj_l2norm<<<640, 256, 0, stream>>>(ex_feat, features, W3, ef_n, f_n);
  fused_sim<<<512, 256, 0, stream>>>(f_n, ef_n, vT, tT, r_acc);
  finalize<<<1024, 256, 0, stream>>>(tT, r_acc, creps, labels, lossp, out);
}